// Round 1
// baseline (885.891 us; speedup 1.0000x reference)
//
#include <hip/hip_runtime.h>
#include <stdint.h>

// SNN forward, max_layer==2 (Mozafari 2018 style):
//   pad(2) -> conv1 (30,6,5,5) -> fire(>15) -> maxpool2x2 -> pad(1)
//   -> conv2 (240,30,3,3) -> fire(>10) -> return (spk, pot)
// Shapes: in (15,6,224,224) f32; out = spk(15,240,112,112) ++ pot(same), f32.

#define N_T   15
#define C1IN  6
#define C1OUT 30
#define H1    224
#define C2OUT 240
#define HP    112          // pooled / layer-2 spatial
#define HPAD  114          // pooled + pad 1
#define POT1_T 15.0f
#define POT2_T 10.0f

// ---------------------------------------------------------------------------
// Kernel A: conv1 + fire + 2x2 maxpool, writes padded uint8 spike map.
// grid: (49 tiles, 15 n), block 256 threads = 16x16 pooled outputs.
// Each thread computes a 2x2 block of conv1 outputs for all 30 channels
// (channel groups of 6), ORs the fires into one pooled spike.
// ---------------------------------------------------------------------------
__global__ __launch_bounds__(256) void conv1_fire_pool(
    const float* __restrict__ in, const float* __restrict__ w1,
    uint8_t* __restrict__ spk)
{
  const int tile = blockIdx.x;          // 0..48
  const int n    = blockIdx.y;          // 0..14
  const int ty = tile / 7, tx = tile % 7;
  const int oy0 = ty * 32, ox0 = tx * 32;   // conv1-output tile origin

  __shared__ float lds[C1IN][36][36];   // padded-input tile

  const int tid = threadIdx.x;
  for (int i = tid; i < C1IN * 36 * 36; i += 256) {
    int ci  = i / 1296;
    int rem = i - ci * 1296;
    int dy  = rem / 36;
    int dx  = rem - dy * 36;
    int y = oy0 + dy - 2;               // original coords (pad=2)
    int x = ox0 + dx - 2;
    float v = 0.0f;
    if ((unsigned)y < (unsigned)H1 && (unsigned)x < (unsigned)H1)
      v = in[((n * C1IN + ci) * H1 + y) * H1 + x];
    lds[ci][dy][dx] = v;
  }
  __syncthreads();

  const int py = tid >> 4;              // pooled-local y, 0..15
  const int px = tid & 15;              // pooled-local x, 0..15
  const int pooled_y = 16 * ty + py;
  const int pooled_x = 16 * tx + px;

  // 5 groups of 6 channels
  for (int g = 0; g < 5; ++g) {
    float acc[6][4];
    #pragma unroll
    for (int c = 0; c < 6; ++c)
      #pragma unroll
      for (int r = 0; r < 4; ++r) acc[c][r] = 0.0f;

    for (int ci = 0; ci < C1IN; ++ci) {
      // 6x6 input window for the 2x2 outputs, held in registers
      float v[6][6];
      #pragma unroll
      for (int iy = 0; iy < 6; ++iy) {
        const float2* p = (const float2*)&lds[ci][2 * py + iy][2 * px];
        float2 a = p[0], b = p[1], c2 = p[2];
        v[iy][0] = a.x; v[iy][1] = a.y;
        v[iy][2] = b.x; v[iy][3] = b.y;
        v[iy][4] = c2.x; v[iy][5] = c2.y;
      }
      #pragma unroll
      for (int c = 0; c < 6; ++c) {
        const float* wp = w1 + ((g * 6 + c) * C1IN + ci) * 25;  // uniform -> s_load
        #pragma unroll
        for (int ky = 0; ky < 5; ++ky) {
          #pragma unroll
          for (int kx = 0; kx < 5; ++kx) {
            const float w = wp[ky * 5 + kx];
            acc[c][0] = fmaf(v[ky    ][kx    ], w, acc[c][0]);
            acc[c][1] = fmaf(v[ky    ][kx + 1], w, acc[c][1]);
            acc[c][2] = fmaf(v[ky + 1][kx    ], w, acc[c][2]);
            acc[c][3] = fmaf(v[ky + 1][kx + 1], w, acc[c][3]);
          }
        }
      }
    }

    #pragma unroll
    for (int c = 0; c < 6; ++c) {
      const bool fire = (acc[c][0] > POT1_T) | (acc[c][1] > POT1_T) |
                        (acc[c][2] > POT1_T) | (acc[c][3] > POT1_T);
      const int ch = g * 6 + c;
      spk[((n * C1OUT + ch) * HPAD + (pooled_y + 1)) * HPAD + (pooled_x + 1)] =
          fire ? (uint8_t)1 : (uint8_t)0;
    }
  }
}

// ---------------------------------------------------------------------------
// Kernel B: conv2 + fire.
// grid: (49 tiles, 15 co-groups, 15 n), block 256 = 16x16 outputs.
// Each thread accumulates 16 output channels; spikes staged in LDS as float,
// weights read with block-uniform indices (scalar loads).
// ---------------------------------------------------------------------------
__global__ __launch_bounds__(256) void conv2_fire(
    const uint8_t* __restrict__ spk, const float* __restrict__ w2,
    float* __restrict__ out_spk, float* __restrict__ out_pot)
{
  const int tile = blockIdx.x;          // 0..48
  const int cog  = blockIdx.y;          // 0..14, co base = cog*16
  const int n    = blockIdx.z;          // 0..14
  const int ty = tile / 7, tx = tile % 7;
  const int y0 = ty * 16, x0 = tx * 16; // output tile origin (padded-in rows y0..y0+17)

  __shared__ float s[C1OUT][18][18];

  const int tid = threadIdx.x;
  for (int i = tid; i < C1OUT * 18 * 18; i += 256) {
    int ci  = i / 324;
    int rem = i - ci * 324;
    int dy  = rem / 18;
    int dx  = rem - dy * 18;
    s[ci][dy][dx] =
        (float)spk[((n * C1OUT + ci) * HPAD + (y0 + dy)) * HPAD + (x0 + dx)];
  }
  __syncthreads();

  const int py = tid >> 4;              // 0..15
  const int px = tid & 15;

  float acc[16];
  #pragma unroll
  for (int u = 0; u < 16; ++u) acc[u] = 0.0f;

  const int co0 = cog * 16;
  for (int ci = 0; ci < C1OUT; ++ci) {
    #pragma unroll
    for (int ky = 0; ky < 3; ++ky) {
      const float v0 = s[ci][py + ky][px    ];
      const float v1 = s[ci][py + ky][px + 1];
      const float v2 = s[ci][py + ky][px + 2];
      const float* wb = w2 + ((size_t)co0 * C1OUT + ci) * 9 + ky * 3; // uniform
      #pragma unroll
      for (int u = 0; u < 16; ++u) {
        const float* wp = wb + (size_t)u * C1OUT * 9;
        acc[u] = fmaf(v0, wp[0], fmaf(v1, wp[1], fmaf(v2, wp[2], acc[u])));
      }
    }
  }

  const int oy = y0 + py, ox = x0 + px;
  #pragma unroll
  for (int u = 0; u < 16; ++u) {
    const float p  = acc[u];
    const bool  f  = p > POT2_T;
    const float pt = f ? p : 0.0f;
    const float sp = f ? 1.0f : 0.0f;
    const int idx = ((n * C2OUT + co0 + u) * HP + oy) * HP + ox;
    out_spk[idx] = sp;
    out_pot[idx] = pt;
  }
}

// ---------------------------------------------------------------------------
extern "C" void kernel_launch(void* const* d_in, const int* in_sizes, int n_in,
                              void* d_out, int out_size, void* d_ws, size_t ws_size,
                              hipStream_t stream)
{
  const float* in = (const float*)d_in[0];
  const float* w1 = (const float*)d_in[1];
  const float* w2 = (const float*)d_in[2];
  // d_in[3] = max_layer (always 2 here)

  float* out = (float*)d_out;
  const size_t pot_off = (size_t)N_T * C2OUT * HP * HP;   // 45,158,400

  uint8_t* spk = (uint8_t*)d_ws;
  const size_t spk_bytes = (size_t)N_T * C1OUT * HPAD * HPAD;  // ~5.85 MB

  // zero the padded spike buffer (ws is poisoned 0xAA before every launch)
  hipMemsetAsync(d_ws, 0, spk_bytes, stream);

  dim3 gridA(49, N_T);
  conv1_fire_pool<<<gridA, 256, 0, stream>>>(in, w1, spk);

  dim3 gridB(49, C2OUT / 16, N_T);
  conv2_fire<<<gridB, 256, 0, stream>>>(spk, w2, out, out + pot_off);
}

// Round 2
// 717.489 us; speedup vs baseline: 1.2347x; 1.2347x over previous
//
#include <hip/hip_runtime.h>
#include <stdint.h>

// SNN forward (Mozafari 2018), max_layer==2:
//   pad(2) -> conv1(30,6,5,5) -> fire(>15) -> maxpool2x2 -> pad(1)
//   -> conv2(240,30,3,3) -> fire(>10) -> out = spk ++ pot (f32)
//
// Implicit-GEMM via bf16 MFMA (16x16x32):
//  conv1: M=15*112*112*4 (pool-interleaved), N=32(30), K=160(150)
//  conv2: M=15*112*112,   N=240,             K=288(270)
// Spikes are exact in bf16; weights bf16-rounded (|err| << 4.36 tolerance,
// fire margins are ~15-sigma so no spike flips).

typedef short short8 __attribute__((ext_vector_type(8)));
typedef float f32x4 __attribute__((ext_vector_type(4)));

#define POT1_T 15.0f
#define POT2_T 10.0f

// ws layout
#define SPK_BYTES 5848200                 // 15*30*114*114 padded uint8 spike map
#define BP2_OFF   5848320                 // 16B aligned
#define BP2_BYTES 138240                  // 9*15*64*8*2  (conv2 B-frags)
#define BP1_OFF   (BP2_OFF + BP2_BYTES)
#define BP1_BYTES 10240                   // 5*2*64*8*2   (conv1 B-frags)

__device__ __forceinline__ unsigned short f2bf(float f) {
  union { float f; unsigned u; } c; c.f = f;
  unsigned u = c.u;
  u += 0x7FFFu + ((u >> 16) & 1u);        // round-to-nearest-even
  return (unsigned short)(u >> 16);
}

// ---------------------------------------------------------------------------
// Pack weights into MFMA B-operand fragment layout:
//   B[n=lane&15][k=(lane>>4)*8+j], stored [s][nsub][lane][8] contiguous 16B.
// ---------------------------------------------------------------------------
__global__ __launch_bounds__(64) void pack_weights(
    const float* __restrict__ w1, const float* __restrict__ w2,
    unsigned short* __restrict__ bp2, unsigned short* __restrict__ bp1)
{
  const int b = blockIdx.x, lane = threadIdx.x;
  const int quad = lane >> 4, nl = lane & 15;
  if (b < 135) {                           // conv2: 9 K-steps x 15 N-subtiles
    const int s = b / 15, nsub = b - s * 15;
    const int ch = nsub * 16 + nl;         // 0..239
    unsigned short* dst = bp2 + (((s * 15 + nsub) * 64 + lane) << 3);
    #pragma unroll
    for (int j = 0; j < 8; ++j) {
      const int k = s * 32 + quad * 8 + j; // k = ci*9+ky*3+kx
      dst[j] = f2bf((k < 270) ? w2[ch * 270 + k] : 0.0f);
    }
  } else {                                 // conv1: 5 K-steps x 2 N-subtiles
    const int bb = b - 135;
    const int s = bb >> 1, nsub = bb & 1;
    const int ch = nsub * 16 + nl;
    unsigned short* dst = bp1 + (((s * 2 + nsub) * 64 + lane) << 3);
    #pragma unroll
    for (int j = 0; j < 8; ++j) {
      const int k = s * 32 + quad * 8 + j; // k = ci*25+ky*5+kx
      dst[j] = f2bf((k < 150 && ch < 30) ? w1[ch * 150 + k] : 0.0f);
    }
  }
}

// ---------------------------------------------------------------------------
// conv1 + fire + maxpool2x2, fused via pool-interleaved M ordering:
//   m = (((n*112+gy)*112+gx))*4 + (dy*2+dx), so each lane's 4 C/D regs
//   (rows m0+quad*4..+3) are exactly one 2x2 pool window.
// A-frags built per-lane directly from global (no LDS: zero cross-lane reuse).
// grid 11760 x 256 threads (4 waves, M_b=64).
// ---------------------------------------------------------------------------
__global__ __launch_bounds__(256) void conv1_mfma(
    const float* __restrict__ in, const unsigned short* __restrict__ bp1,
    uint8_t* __restrict__ spk)
{
  __shared__ __attribute__((aligned(16))) unsigned short Blds[5 * 2 * 64 * 8];
  const int tid = threadIdx.x;
  for (int i = tid; i < 640; i += 256)     // 10 KB flat copy
    ((uint4*)Blds)[i] = ((const uint4*)bp1)[i];
  __syncthreads();

  const int wave = tid >> 6, lane = tid & 63;
  const int quad = lane >> 4, nl = lane & 15;
  const int m0 = blockIdx.x * 64 + wave * 16;

  // A-side coords for this lane's row m = m0 + nl
  const int m = m0 + nl;
  const int sub = m & 3, g = m >> 2;
  const int gx = g % 112, t = g / 112;
  const int gy = t % 112, n = t / 112;
  const int y0 = gy * 2 + (sub >> 1) - 2;  // pad=2
  const int x0 = gx * 2 + (sub & 1) - 2;
  const float* inb = in + (size_t)n * (6 * 224 * 224);

  f32x4 acc0 = {0.f, 0.f, 0.f, 0.f}, acc1 = {0.f, 0.f, 0.f, 0.f};
  for (int s = 0; s < 5; ++s) {
    short8 a;
    const int kb = s * 32 + quad * 8;
    #pragma unroll
    for (int j = 0; j < 8; ++j) {
      const int k = kb + j;
      float v = 0.0f;
      if (k < 150) {
        const int ci = k / 25, r = k - ci * 25;
        const int ky = r / 5, kx = r - ky * 5;
        const int y = y0 + ky, xx = x0 + kx;
        if ((unsigned)y < 224u && (unsigned)xx < 224u)
          v = inb[(ci * 224 + y) * 224 + xx];
      }
      a[j] = (short)f2bf(v);
    }
    const short8 b0 = *(const short8*)&Blds[((s * 2 + 0) * 64 + lane) * 8];
    const short8 b1 = *(const short8*)&Blds[((s * 2 + 1) * 64 + lane) * 8];
    acc0 = __builtin_amdgcn_mfma_f32_16x16x32_bf16(a, b0, acc0, 0, 0, 0);
    acc1 = __builtin_amdgcn_mfma_f32_16x16x32_bf16(a, b1, acc1, 0, 0, 0);
  }

  // Epilogue: C/D col = lane&15 = channel, rows quad*4+reg = one pool group.
  const int gq = (m0 >> 2) + quad;
  const int pgx = gq % 112, tq = gq / 112;
  const int pgy = tq % 112, nq = tq / 112;
  const bool f0 = (acc0[0] > POT1_T) | (acc0[1] > POT1_T) |
                  (acc0[2] > POT1_T) | (acc0[3] > POT1_T);
  const bool f1 = (acc1[0] > POT1_T) | (acc1[1] > POT1_T) |
                  (acc1[2] > POT1_T) | (acc1[3] > POT1_T);
  const int rowoff = (pgy + 1) * 114 + (pgx + 1);     // pad=1 built in
  spk[(nq * 30 + nl) * 12996 + rowoff] = f0 ? 1 : 0;
  if (nl + 16 < 30)
    spk[(nq * 30 + nl + 16) * 12996 + rowoff] = f1 ? 1 : 0;
}

// ---------------------------------------------------------------------------
// conv2 + fire. M tile 64 (4 waves x 16), N tile 48 (3 subtiles/wave), K=288.
// A-frags per-lane from padded uint8 spikes (0 -> 0, 1 -> 0x3F80 bf16 one).
// grid (2940, 5) x 256 threads.
// ---------------------------------------------------------------------------
__global__ __launch_bounds__(256) void conv2_mfma(
    const uint8_t* __restrict__ spk, const unsigned short* __restrict__ bp2,
    float* __restrict__ out_spk, float* __restrict__ out_pot)
{
  __shared__ __attribute__((aligned(16))) unsigned short Blds[9 * 3 * 64 * 8];
  const int tid = threadIdx.x;
  const int ntile = blockIdx.y;            // 0..4, channels ntile*48..+47
  for (int i = tid; i < 1728; i += 256) {  // 27.6 KB B stage
    const int s = i / 192, r = i - s * 192;
    const int j3 = r >> 6, lane2 = r & 63;
    ((uint4*)Blds)[i] =
        ((const uint4*)bp2)[(s * 15 + ntile * 3 + j3) * 64 + lane2];
  }
  __syncthreads();

  const int wave = tid >> 6, lane = tid & 63;
  const int quad = lane >> 4, nl = lane & 15;
  const int m0 = blockIdx.x * 64 + wave * 16;
  const int m = m0 + nl;                   // A-side row
  const int x = m % 112, t = m / 112;
  const int y = t % 112, n = t / 112;
  const uint8_t* sb = spk + (size_t)n * (30 * 12996) + y * 114 + x;

  f32x4 acc0 = {0.f,0.f,0.f,0.f}, acc1 = {0.f,0.f,0.f,0.f}, acc2 = {0.f,0.f,0.f,0.f};
  for (int s = 0; s < 9; ++s) {
    short8 a;
    const int kb = s * 32 + quad * 8;
    #pragma unroll
    for (int j = 0; j < 8; ++j) {
      const int k = kb + j;
      unsigned short v = 0;
      if (k < 270) {
        const int ci = k / 9, r = k - ci * 9;
        const int ky = r / 3, kx = r - ky * 3;
        v = sb[ci * 12996 + ky * 114 + kx] ? (unsigned short)0x3F80
                                           : (unsigned short)0;
      }
      a[j] = (short)v;
    }
    const short8 b0 = *(const short8*)&Blds[((s * 3 + 0) * 64 + lane) * 8];
    const short8 b1 = *(const short8*)&Blds[((s * 3 + 1) * 64 + lane) * 8];
    const short8 b2 = *(const short8*)&Blds[((s * 3 + 2) * 64 + lane) * 8];
    acc0 = __builtin_amdgcn_mfma_f32_16x16x32_bf16(a, b0, acc0, 0, 0, 0);
    acc1 = __builtin_amdgcn_mfma_f32_16x16x32_bf16(a, b1, acc1, 0, 0, 0);
    acc2 = __builtin_amdgcn_mfma_f32_16x16x32_bf16(a, b2, acc2, 0, 0, 0);
  }

  // Epilogue: rows mrow..mrow+3 contiguous in x (mrow%4==0, 112%4==0).
  const int mrow = m0 + quad * 4;
  const int xr = mrow % 112, tr = mrow / 112;
  const int yr = tr % 112, nr = tr / 112;
  const f32x4 accs[3] = {acc0, acc1, acc2};
  #pragma unroll
  for (int j3 = 0; j3 < 3; ++j3) {
    const int ch = ntile * 48 + j3 * 16 + nl;
    const size_t o = ((size_t)(nr * 240 + ch) * 112 + yr) * 112 + xr;
    f32x4 sp, pt;
    #pragma unroll
    for (int rr = 0; rr < 4; ++rr) {
      const float p = accs[j3][rr];
      const bool f = p > POT2_T;
      sp[rr] = f ? 1.0f : 0.0f;
      pt[rr] = f ? p : 0.0f;
    }
    *(f32x4*)(out_spk + o) = sp;           // 16B aligned: xr%4==0
    *(f32x4*)(out_pot + o) = pt;
  }
}

// ---------------------------------------------------------------------------
extern "C" void kernel_launch(void* const* d_in, const int* in_sizes, int n_in,
                              void* d_out, int out_size, void* d_ws, size_t ws_size,
                              hipStream_t stream)
{
  const float* in = (const float*)d_in[0];
  const float* w1 = (const float*)d_in[1];
  const float* w2 = (const float*)d_in[2];
  float* out = (float*)d_out;

  uint8_t* spk = (uint8_t*)d_ws;
  unsigned short* bp2 = (unsigned short*)((char*)d_ws + BP2_OFF);
  unsigned short* bp1 = (unsigned short*)((char*)d_ws + BP1_OFF);

  hipMemsetAsync(d_ws, 0, SPK_BYTES, stream);          // zero spike padding
  pack_weights<<<145, 64, 0, stream>>>(w1, w2, bp2, bp1);
  conv1_mfma<<<11760, 256, 0, stream>>>(in, bp1, spk);
  conv2_mfma<<<dim3(2940, 5), 256, 0, stream>>>(
      spk, bp2, out, out + (size_t)15 * 240 * 112 * 112);
}

// Round 3
// 557.163 us; speedup vs baseline: 1.5900x; 1.2878x over previous
//
#include <hip/hip_runtime.h>
#include <stdint.h>

// SNN forward (Mozafari 2018), max_layer==2:
//   pad(2) -> conv1(30,6,5,5) -> fire(>15) -> maxpool2x2 -> pad(1)
//   -> conv2(240,30,3,3) -> fire(>10) -> out = spk ++ pot (f32)
//
// bf16 MFMA implicit GEMM. K-axis remapped so per-K-step A addresses are
// loop-invariant (no div/mod in hot loops):
//   conv1: k = ci*32 + (ky*5+kx)      K=192 (6 steps), slots r>=25 zero
//   conv2: k = (ky*3+kx)*32 + ci      K=288 (9 steps), slots ci>=30 zero
// A-side garbage in zero-B slots is finite (ws poison 0xAA = tiny bf16), so
// contributes exactly 0. Guard tail keeps over-reads inside ws.

typedef short short8 __attribute__((ext_vector_type(8)));
typedef float f32x4 __attribute__((ext_vector_type(4)));

#define POT1_T 15.0f
#define POT2_T 10.0f

// ---- ws layout (all 16B aligned) ----
#define SPK16_BYTES (15*30*114*114*2)          // 11,696,400  bf16 spike map (padded)
#define BP2_OFF     SPK16_BYTES
#define BP2_BYTES   (9*15*64*8*2)              // 138,240
#define BP1_OFF     (BP2_OFF + BP2_BYTES)
#define BP1_BYTES   (6*2*64*8*2)               // 12,288
#define IN16_OFF    (BP1_OFF + BP1_BYTES)      // 11,846,928
#define IN16_ELEMS  (90*228*228)               // 4,678,560 (15n x 6ci, padded)
// total ws use: IN16_OFF + IN16_ELEMS*2 + 4KB guard ~= 21.2 MB

__device__ __forceinline__ unsigned short f2bf(float f) {
  union { float f; unsigned u; } c; c.f = f;
  unsigned u = c.u;
  u += 0x7FFFu + ((u >> 16) & 1u);             // RNE
  return (unsigned short)(u >> 16);
}

// ---------------------------------------------------------------------------
// Input -> padded bf16 (n,ci,228,228), pad=2 ring zeroed by writing full planes
// ---------------------------------------------------------------------------
__global__ __launch_bounds__(256) void cvt_input(
    const float* __restrict__ in, unsigned short* __restrict__ in16)
{
  const int i = blockIdx.x * 256 + threadIdx.x;
  if (i >= IN16_ELEMS) return;
  const int x = i % 228, t = i / 228;
  const int y = t % 228, c = t / 228;          // c = n*6+ci, 0..89
  const int xi = x - 2, yi = y - 2;
  float v = 0.0f;
  if ((unsigned)xi < 224u && (unsigned)yi < 224u)
    v = in[(c * 224 + yi) * 224 + xi];
  in16[i] = f2bf(v);
}

// ---------------------------------------------------------------------------
// Weights -> MFMA B-frag layout [step][nsub][lane][8], remapped K (see header)
// ---------------------------------------------------------------------------
__global__ __launch_bounds__(64) void pack_weights(
    const float* __restrict__ w1, const float* __restrict__ w2,
    unsigned short* __restrict__ bp2, unsigned short* __restrict__ bp1)
{
  const int b = blockIdx.x, lane = threadIdx.x;
  const int quad = lane >> 4, nl = lane & 15;
  if (b < 135) {                               // conv2: 9 steps x 15 nsub
    const int s = b / 15, nsub = b - s * 15;   // s = ky*3+kx
    const int ch = nsub * 16 + nl;
    unsigned short* dst = bp2 + (((s * 15 + nsub) * 64 + lane) << 3);
    #pragma unroll
    for (int j = 0; j < 8; ++j) {
      const int ci = quad * 8 + j;             // k%32
      dst[j] = f2bf((ci < 30) ? w2[ch * 270 + ci * 9 + s] : 0.0f);
    }
  } else {                                     // conv1: 6 steps x 2 nsub
    const int bb = b - 135;
    const int s = bb >> 1, nsub = bb & 1;      // s = ci
    const int ch = nsub * 16 + nl;
    unsigned short* dst = bp1 + (((s * 2 + nsub) * 64 + lane) << 3);
    #pragma unroll
    for (int j = 0; j < 8; ++j) {
      const int r = quad * 8 + j;              // ky*5+kx
      dst[j] = f2bf((r < 25 && ch < 30) ? w1[ch * 150 + s * 25 + r] : 0.0f);
    }
  }
}

// ---------------------------------------------------------------------------
// conv1 + fire + maxpool. Pool-interleaved M: m=(((n*112+gy)*112+gx))*4+sub,
// so each lane's 4 C/D rows = one 2x2 pool window. No LDS, no barrier.
// grid 11760 x 256 (4 waves x 16 rows).
// ---------------------------------------------------------------------------
__global__ __launch_bounds__(256) void conv1_mfma(
    const unsigned short* __restrict__ in16,
    const unsigned short* __restrict__ bp1,
    unsigned short* __restrict__ spk16)
{
  const int tid = threadIdx.x;
  const int wave = tid >> 6, lane = tid & 63;
  const int quad = lane >> 4, nl = lane & 15;
  const int m0 = blockIdx.x * 64 + wave * 16;

  const int m = m0 + nl;
  const int sub = m & 3, g = m >> 2;
  const int gx = g % 112, t = g / 112;
  const int gy = t % 112, n = t / 112;
  const int y0 = gy * 2 + (sub >> 1);          // padded coords
  const int x0 = gx * 2 + (sub & 1);

  // loop-invariant lane offsets: r = quad*8+j -> (ky,kx); r>=25 reads junk
  // past the window (in-bounds of ws, B=0 there).
  unsigned off[8];
  #pragma unroll
  for (int j = 0; j < 8; ++j) {
    const int r = quad * 8 + j;
    off[j] = (unsigned)((r / 5) * 228 + (r % 5));
  }
  const unsigned base = (unsigned)(n * (6 * 51984) + y0 * 228 + x0);

  f32x4 acc0 = {0.f,0.f,0.f,0.f}, acc1 = {0.f,0.f,0.f,0.f};
  #pragma unroll
  for (int s = 0; s < 6; ++s) {                // s = ci
    short8 a;
    #pragma unroll
    for (int j = 0; j < 8; ++j)
      a[j] = (short)in16[base + (unsigned)(s * 51984) + off[j]];
    const short8 b0 = *(const short8*)(bp1 + (((s * 2 + 0) * 64 + lane) << 3));
    const short8 b1 = *(const short8*)(bp1 + (((s * 2 + 1) * 64 + lane) << 3));
    acc0 = __builtin_amdgcn_mfma_f32_16x16x32_bf16(a, b0, acc0, 0, 0, 0);
    acc1 = __builtin_amdgcn_mfma_f32_16x16x32_bf16(a, b1, acc1, 0, 0, 0);
  }

  // epilogue: col=ch, rows quad*4..+3 = one pool window; write bf16 spike
  const int gq = (m0 >> 2) + quad;
  const int pgx = gq % 112, tq = gq / 112;
  const int pgy = tq % 112, nq = tq / 112;
  const bool f0 = (acc0[0] > POT1_T) | (acc0[1] > POT1_T) |
                  (acc0[2] > POT1_T) | (acc0[3] > POT1_T);
  const bool f1 = (acc1[0] > POT1_T) | (acc1[1] > POT1_T) |
                  (acc1[2] > POT1_T) | (acc1[3] > POT1_T);
  const int rowoff = (pgy + 1) * 114 + (pgx + 1);
  spk16[(nq * 30 + nl) * 12996 + rowoff] = f0 ? (unsigned short)0x3F80 : (unsigned short)0;
  if (nl + 16 < 30)
    spk16[(nq * 30 + nl + 16) * 12996 + rowoff] = f1 ? (unsigned short)0x3F80 : (unsigned short)0;
}

// ---------------------------------------------------------------------------
// conv2 + fire: M tile 64 (4 waves x 16 rows), N = all 240 (15 subtiles/wave).
// Each A-frag feeds 15 MFMAs. Per-step A loads: invariant voff + imm offset.
// grid 2940 x 256. No LDS.
// ---------------------------------------------------------------------------
__global__ __launch_bounds__(256, 2) void conv2_mfma(
    const unsigned short* __restrict__ spk16,
    const unsigned short* __restrict__ bp2,
    float* __restrict__ out_spk, float* __restrict__ out_pot)
{
  const int tid = threadIdx.x;
  const int wave = tid >> 6, lane = tid & 63;
  const int quad = lane >> 4, nl = lane & 15;
  const int m0 = blockIdx.x * 64 + wave * 16;

  const int m = m0 + nl;
  const int x = m % 112, t = m / 112;
  const int y = t % 112, n = t / 112;

  // invariant lane offsets: voff[j] for channel ci = quad*8+j (ci>=30: junk
  // reads land in later ws regions, finite bf16, B=0 -> contribute 0)
  unsigned voff[8];
  #pragma unroll
  for (int j = 0; j < 8; ++j)
    voff[j] = (unsigned)(n * (30 * 12996) + y * 114 + x + (quad * 8 + j) * 12996);

  f32x4 acc[15];
  #pragma unroll
  for (int u = 0; u < 15; ++u) acc[u] = (f32x4){0.f, 0.f, 0.f, 0.f};

  #pragma unroll
  for (int s = 0; s < 9; ++s) {                // s = ky*3+kx, imm = ky*114+kx
    const unsigned imm = (unsigned)((s / 3) * 114 + (s % 3));  // compile-time
    short8 a;
    #pragma unroll
    for (int j = 0; j < 8; ++j)
      a[j] = (short)spk16[voff[j] + imm];
    #pragma unroll
    for (int u = 0; u < 15; ++u) {
      const short8 b = *(const short8*)(bp2 + (((s * 15 + u) * 64 + lane) << 3));
      acc[u] = __builtin_amdgcn_mfma_f32_16x16x32_bf16(a, b, acc[u], 0, 0, 0);
    }
  }

  // epilogue: rows mrow..mrow+3 contiguous in x (m0%4==0, 112%4==0)
  const int mrow = m0 + quad * 4;
  const int xr = mrow % 112, tr = mrow / 112;
  const int yr = tr % 112, nr = tr / 112;
  #pragma unroll
  for (int u = 0; u < 15; ++u) {
    const int ch = u * 16 + nl;
    const size_t o = ((size_t)(nr * 240 + ch) * 112 + yr) * 112 + xr;
    f32x4 sp, pt;
    #pragma unroll
    for (int rr = 0; rr < 4; ++rr) {
      const float p = acc[u][rr];
      const bool f = p > POT2_T;
      sp[rr] = f ? 1.0f : 0.0f;
      pt[rr] = f ? p : 0.0f;
    }
    *(f32x4*)(out_spk + o) = sp;
    *(f32x4*)(out_pot + o) = pt;
  }
}

// ---------------------------------------------------------------------------
extern "C" void kernel_launch(void* const* d_in, const int* in_sizes, int n_in,
                              void* d_out, int out_size, void* d_ws, size_t ws_size,
                              hipStream_t stream)
{
  const float* in = (const float*)d_in[0];
  const float* w1 = (const float*)d_in[1];
  const float* w2 = (const float*)d_in[2];
  float* out = (float*)d_out;

  unsigned short* spk16 = (unsigned short*)d_ws;
  unsigned short* bp2   = (unsigned short*)((char*)d_ws + BP2_OFF);
  unsigned short* bp1   = (unsigned short*)((char*)d_ws + BP1_OFF);
  unsigned short* in16  = (unsigned short*)((char*)d_ws + IN16_OFF);

  hipMemsetAsync(d_ws, 0, SPK16_BYTES, stream);          // spike map padding
  cvt_input<<<(IN16_ELEMS + 255) / 256, 256, 0, stream>>>(in, in16);
  pack_weights<<<147, 64, 0, stream>>>(w1, w2, bp2, bp1);
  conv1_mfma<<<11760, 256, 0, stream>>>(in16, bp1, spk16);
  conv2_mfma<<<2940, 256, 0, stream>>>(
      spk16, bp2, out, out + (size_t)15 * 240 * 112 * 112);
}

// Round 5
// 520.877 us; speedup vs baseline: 1.7008x; 1.0697x over previous
//
#include <hip/hip_runtime.h>
#include <stdint.h>

// SNN forward (Mozafari 2018), max_layer==2:
//   pad(2) -> conv1(30,6,5,5) -> fire(>15) -> maxpool2x2 -> pad(1)
//   -> conv2(240,30,3,3) -> fire(>10) -> out = spk ++ pot (f32)
//
// f16 MFMA implicit GEMM (spikes exact in f16; weights RNE, input RTZ;
// worst-case pot2 error ~0.07 << 4.36 tolerance).
//
// K-mappings chosen so every A-fragment is a contiguous vector load:
//  conv1: step s -> (ci,ky) pair, quad -> row, j -> kx (kx>=5: B=0).
//         A-frag = 8 consecutive f32 of one padded input row -> 2x dwordx4
//         + 4x v_cvt_pkrtz. K=256 (8 steps).
//  conv2: step s = ky*3+kx, lane k-index = ci (ch-interleaved spike map
//         (n,y,x,32)) -> A-frag = one aligned b128 load. K=288 (9 steps).

typedef _Float16 half8  __attribute__((ext_vector_type(8)));
typedef __fp16   fp16x2 __attribute__((ext_vector_type(2)));
typedef float f32x4  __attribute__((ext_vector_type(4)));
typedef float f32x4u __attribute__((ext_vector_type(4), aligned(4)));

#define POT1_T 15.0f
#define POT2_T 10.0f

// ---- ws layout (all 16B aligned) ----
#define SPK_ELEMS  (15*114*114*32)            // 6,238,080 f16 (ch-interleaved, padded)
#define SPK_BYTES  (SPK_ELEMS*2)              // 12,476,160
#define BP2_OFF    SPK_BYTES
#define BP2_BYTES  (9*15*64*8*2)              // 138,240
#define BP1_OFF    (BP2_OFF + BP2_BYTES)
#define BP1_BYTES  (8*2*64*8*2)               // 16,384
#define IN32_OFF   (BP1_OFF + BP1_BYTES)
#define IN32_ELEMS (90*228*228)               // 4,678,560 f32 (padded input)
// total ~31.3 MB + a few bytes of junk over-read (kx 5..7 slots, B=0) -- ws is GBs.

__device__ __forceinline__ unsigned short f2h(float v) {
  union { _Float16 h; unsigned short u; } c;
  c.h = (_Float16)v;                          // RNE
  return c.u;
}

// ---------------------------------------------------------------------------
// Input -> padded f32 (n*6, 228, 228), pad=2 ring zeroed
// ---------------------------------------------------------------------------
__global__ __launch_bounds__(256) void pad_input(
    const float* __restrict__ in, float* __restrict__ in32)
{
  const int i = blockIdx.x * 256 + threadIdx.x;
  if (i >= IN32_ELEMS) return;
  const int xx = i % 228, t = i / 228;
  const int yy = t % 228, c = t / 228;
  const int xi = xx - 2, yi = yy - 2;
  float v = 0.0f;
  if ((unsigned)xi < 224u && (unsigned)yi < 224u)
    v = in[(c * 224 + yi) * 224 + xi];
  in32[i] = v;
}

// ---------------------------------------------------------------------------
// Weights -> f16 MFMA B-frag layout [step][nsub][lane][8]
// ---------------------------------------------------------------------------
__global__ __launch_bounds__(64) void pack_weights(
    const float* __restrict__ w1, const float* __restrict__ w2,
    unsigned short* __restrict__ bp2, unsigned short* __restrict__ bp1)
{
  const int b = blockIdx.x, lane = threadIdx.x;
  const int quad = lane >> 4, nl = lane & 15;
  if (b < 135) {                               // conv2: 9 steps x 15 nsub
    const int s = b / 15, nsub = b - s * 15;   // s = ky*3+kx
    const int ch = nsub * 16 + nl;
    unsigned short* dst = bp2 + (((s * 15 + nsub) * 64 + lane) << 3);
    #pragma unroll
    for (int j = 0; j < 8; ++j) {
      const int ci = quad * 8 + j;
      dst[j] = f2h((ci < 30) ? w2[ch * 270 + ci * 9 + s] : 0.0f);
    }
  } else {                                     // conv1: 8 steps x 2 nsub
    const int bb = b - 135;
    const int s = bb >> 1, nsub = bb & 1;
    const int ch = nsub * 16 + nl;
    unsigned short* dst = bp1 + (((s * 2 + nsub) * 64 + lane) << 3);
    #pragma unroll
    for (int j = 0; j < 8; ++j) {
      int ci, ky;
      bool ok = (ch < 30) && (j < 5);
      if (s < 6)       { ci = s;        ky = quad; }
      else if (s == 6) { ci = quad;     ky = 4;    }
      else             { ci = 4 + quad; ky = 4; ok = ok && (quad < 2); }
      float v = 0.0f;
      if (ok) v = w1[ch * 150 + ci * 25 + ky * 5 + j];
      dst[j] = f2h(v);
    }
  }
}

// ---------------------------------------------------------------------------
// conv1 + fire + maxpool2x2. Pool-interleaved M (4 C/D rows = one 2x2 pool
// window). Per step: 2 dwordx4 A loads + 4 cvt_pkrtz + 2 B b128 + 2 MFMA.
// grid 11760 x 256 (4 waves x 16 rows). No LDS, no barrier.
// ---------------------------------------------------------------------------
__global__ __launch_bounds__(256) void conv1_mfma(
    const float* __restrict__ in32,
    const unsigned short* __restrict__ bp1,
    unsigned short* __restrict__ spk16)
{
  const int tid = threadIdx.x;
  const int wave = tid >> 6, lane = tid & 63;
  const int quad = lane >> 4, nl = lane & 15;
  const int m0 = blockIdx.x * 64 + wave * 16;

  const int m = m0 + nl;
  const int sub = m & 3, g = m >> 2;
  const int gx = g % 112, t = g / 112;
  const int gy = t % 112, n = t / 112;
  const int y0 = gy * 2 + (sub >> 1);          // padded coords
  const int x0 = gx * 2 + (sub & 1);

  const float* nbase = in32 + (size_t)n * (6 * 51984);
  // s<6 rows: plane s, row y0+quad; s==6: plane quad, row y0+4;
  // s==7: plane 4+(quad&1), row y0+4 (quads 2,3 read real data, B=0)
  const float* rq  = nbase + (y0 + quad) * 228 + x0;
  const float* r4a = nbase + (size_t)quad * 51984 + (y0 + 4) * 228 + x0;
  const float* r4b = nbase + (size_t)(4 + (quad & 1)) * 51984 + (y0 + 4) * 228 + x0;

  f32x4 acc0 = {0.f,0.f,0.f,0.f}, acc1 = {0.f,0.f,0.f,0.f};
  const half8* bptr = (const half8*)bp1;

  #pragma unroll
  for (int s = 0; s < 8; ++s) {
    const float* p = (s < 6) ? (rq + s * 51984) : (s == 6 ? r4a : r4b);
    const f32x4u v0 = *(const f32x4u*)p;
    const f32x4u v1 = *(const f32x4u*)(p + 4);
    union { half8 h; fp16x2 h2[4]; } A;
    A.h2[0] = __builtin_amdgcn_cvt_pkrtz(v0.x, v0.y);
    A.h2[1] = __builtin_amdgcn_cvt_pkrtz(v0.z, v0.w);
    A.h2[2] = __builtin_amdgcn_cvt_pkrtz(v1.x, v1.y);
    A.h2[3] = __builtin_amdgcn_cvt_pkrtz(v1.z, v1.w);
    const half8 b0 = bptr[(s * 2 + 0) * 64 + lane];
    const half8 b1 = bptr[(s * 2 + 1) * 64 + lane];
    acc0 = __builtin_amdgcn_mfma_f32_16x16x32_f16(A.h, b0, acc0, 0, 0, 0);
    acc1 = __builtin_amdgcn_mfma_f32_16x16x32_f16(A.h, b1, acc1, 0, 0, 0);
  }

  // epilogue: quad's 4 C/D rows = pool window of group gq; ch-interleaved
  // spike write: 16 lanes x 2B contiguous per quad.
  const int gq = (m0 >> 2) + quad;
  const int pgx = gq % 112, tq = gq / 112;
  const int pgy = tq % 112, nq = tq / 112;
  const bool f0 = (acc0[0] > POT1_T) | (acc0[1] > POT1_T) |
                  (acc0[2] > POT1_T) | (acc0[3] > POT1_T);
  const bool f1 = (acc1[0] > POT1_T) | (acc1[1] > POT1_T) |
                  (acc1[2] > POT1_T) | (acc1[3] > POT1_T);
  const size_t o = ((size_t)(nq * 114 + pgy + 1) * 114 + (pgx + 1)) * 32 + nl;
  spk16[o] = f0 ? (unsigned short)0x3C00 : (unsigned short)0;
  if (nl < 14)                                  // ch nl+16 < 30
    spk16[o + 16] = f1 ? (unsigned short)0x3C00 : (unsigned short)0;
}

// ---------------------------------------------------------------------------
// conv2 + fire: M=16/wave, N=240 (15 subtiles). A-frag = 1 aligned b128 load
// per step (ch-interleaved spikes; ch 30/31 zeroed by memset -> B=0 slots).
// grid 2940 x 256.
// ---------------------------------------------------------------------------
__global__ __launch_bounds__(256, 2) void conv2_mfma(
    const unsigned short* __restrict__ spk16,
    const unsigned short* __restrict__ bp2,
    float* __restrict__ out_spk, float* __restrict__ out_pot)
{
  const int tid = threadIdx.x;
  const int wave = tid >> 6, lane = tid & 63;
  const int quad = lane >> 4, nl = lane & 15;
  const int m0 = blockIdx.x * 64 + wave * 16;

  const int m = m0 + nl;
  const int x = m % 112, t = m / 112;
  const int y = t % 112, n = t / 112;
  const unsigned short* abase =
      spk16 + ((size_t)(n * 114 + y) * 114 + x) * 32 + quad * 8;

  f32x4 acc[15];
  #pragma unroll
  for (int u = 0; u < 15; ++u) acc[u] = (f32x4){0.f, 0.f, 0.f, 0.f};

  const half8* bptr = (const half8*)bp2;
  #pragma unroll
  for (int s = 0; s < 9; ++s) {                // s = ky*3+kx
    const int ky = s / 3, kx = s - ky * 3;     // compile-time under unroll
    const half8 a = *(const half8*)(abase + (ky * 114 + kx) * 32);
    #pragma unroll
    for (int u = 0; u < 15; ++u) {
      const half8 b = bptr[(s * 15 + u) * 64 + lane];
      acc[u] = __builtin_amdgcn_mfma_f32_16x16x32_f16(a, b, acc[u], 0, 0, 0);
    }
  }

  // epilogue: rows mrow..mrow+3 contiguous in x (m0%4==0, 112%4==0)
  const int mrow = m0 + quad * 4;
  const int xr = mrow % 112, tr = mrow / 112;
  const int yr = tr % 112, nr = tr / 112;
  #pragma unroll
  for (int u = 0; u < 15; ++u) {
    const int ch = u * 16 + nl;
    const size_t o = ((size_t)(nr * 240 + ch) * 112 + yr) * 112 + xr;
    f32x4 sp, pt;
    #pragma unroll
    for (int rr = 0; rr < 4; ++rr) {
      const float p = acc[u][rr];
      const bool f = p > POT2_T;
      sp[rr] = f ? 1.0f : 0.0f;
      pt[rr] = f ? p : 0.0f;
    }
    *(f32x4*)(out_spk + o) = sp;
    *(f32x4*)(out_pot + o) = pt;
  }
}

// ---------------------------------------------------------------------------
extern "C" void kernel_launch(void* const* d_in, const int* in_sizes, int n_in,
                              void* d_out, int out_size, void* d_ws, size_t ws_size,
                              hipStream_t stream)
{
  const float* in = (const float*)d_in[0];
  const float* w1 = (const float*)d_in[1];
  const float* w2 = (const float*)d_in[2];
  float* out = (float*)d_out;

  unsigned short* spk16 = (unsigned short*)d_ws;
  unsigned short* bp2   = (unsigned short*)((char*)d_ws + BP2_OFF);
  unsigned short* bp1   = (unsigned short*)((char*)d_ws + BP1_OFF);
  float*          in32  = (float*)((char*)d_ws + IN32_OFF);

  (void)hipMemsetAsync(d_ws, 0, SPK_BYTES, stream);  // spike pad ring + ch 30/31
  pad_input<<<(IN32_ELEMS + 255) / 256, 256, 0, stream>>>(in, in32);
  pack_weights<<<151, 64, 0, stream>>>(w1, w2, bp2, bp1);
  conv1_mfma<<<11760, 256, 0, stream>>>(in32, bp1, spk16);
  conv2_mfma<<<2940, 256, 0, stream>>>(
      spk16, bp2, out, out + (size_t)15 * 240 * 112 * 112);
}

// Round 6
// 515.641 us; speedup vs baseline: 1.7180x; 1.0102x over previous
//
#include <hip/hip_runtime.h>
#include <stdint.h>

// SNN forward (Mozafari 2018), max_layer==2:
//   pad(2) -> conv1(30,6,5,5) -> fire(>15) -> maxpool2x2 -> pad(1)
//   -> conv2(240,30,3,3) -> fire(>10) -> out = spk ++ pot (f32)
//
// f16 MFMA implicit GEMM. K-mappings make every A-fragment a contiguous
// vector load:
//  conv1: step s -> (ci,ky), quad -> row, j -> kx (kx>=5: B=0).
//         A-frag = 8 consecutive f32 -> 2x dwordx4 + 4x v_cvt_pkrtz. K=256.
//  conv2: step s = ky*3+kx, lane k-index = ci (ch-interleaved spike map
//         (n,y,x,32)) -> A-frag = one aligned b128 load. K=288.
// conv2 does M=32/wave (2 chunks share each B-frag) to halve B L2 traffic,
// and uses nontemporal stores for the 361 MB output (don't thrash L2).

typedef _Float16 half8  __attribute__((ext_vector_type(8)));
typedef __fp16   fp16x2 __attribute__((ext_vector_type(2)));
typedef float f32x4  __attribute__((ext_vector_type(4)));
typedef float f32x4u __attribute__((ext_vector_type(4), aligned(4)));

#define POT1_T 15.0f
#define POT2_T 10.0f

// ---- ws layout (all 16B aligned) ----
#define SPK_ELEMS  (15*114*114*32)            // 6,238,080 f16 (ch-interleaved, padded)
#define SPK_BYTES  (SPK_ELEMS*2)              // 12,476,160
#define BP2_OFF    SPK_BYTES
#define BP2_BYTES  (9*15*64*8*2)              // 138,240
#define BP1_OFF    (BP2_OFF + BP2_BYTES)
#define BP1_BYTES  (8*2*64*8*2)               // 16,384
#define IN32_OFF   (BP1_OFF + BP1_BYTES)
#define IN32_ELEMS (90*228*228)               // 4,678,560 f32 (padded input)

#define PAD_BLOCKS ((IN32_ELEMS + 255) / 256) // 18276

__device__ __forceinline__ unsigned short f2h(float v) {
  union { _Float16 h; unsigned short u; } c;
  c.h = (_Float16)v;                          // RNE
  return c.u;
}

// ---------------------------------------------------------------------------
// prep: pad input to f32 (n*6,228,228)  +  pack weights to MFMA B-frag layout
// [step][nsub][lane][8] (fused to save a dispatch).
// ---------------------------------------------------------------------------
__global__ __launch_bounds__(256) void prep(
    const float* __restrict__ in, const float* __restrict__ w1,
    const float* __restrict__ w2, float* __restrict__ in32,
    unsigned short* __restrict__ bp2, unsigned short* __restrict__ bp1)
{
  const int blk = blockIdx.x;
  if (blk < PAD_BLOCKS) {
    const int i = blk * 256 + threadIdx.x;
    if (i >= IN32_ELEMS) return;
    const int xx = i % 228, t = i / 228;
    const int yy = t % 228, c = t / 228;
    const int xi = xx - 2, yi = yy - 2;
    float v = 0.0f;
    if ((unsigned)xi < 224u && (unsigned)yi < 224u)
      v = in[(c * 224 + yi) * 224 + xi];
    in32[i] = v;
    return;
  }
  if (threadIdx.x >= 64) return;
  const int b = blk - PAD_BLOCKS;              // 0..150
  const int lane = threadIdx.x;
  const int quad = lane >> 4, nl = lane & 15;
  if (b < 135) {                               // conv2: 9 steps x 15 nsub
    const int s = b / 15, nsub = b - s * 15;   // s = ky*3+kx
    const int ch = nsub * 16 + nl;
    unsigned short* dst = bp2 + (((s * 15 + nsub) * 64 + lane) << 3);
    #pragma unroll
    for (int j = 0; j < 8; ++j) {
      const int ci = quad * 8 + j;
      dst[j] = f2h((ci < 30) ? w2[ch * 270 + ci * 9 + s] : 0.0f);
    }
  } else {                                     // conv1: 8 steps x 2 nsub
    const int bb = b - 135;
    const int s = bb >> 1, nsub = bb & 1;
    const int ch = nsub * 16 + nl;
    unsigned short* dst = bp1 + (((s * 2 + nsub) * 64 + lane) << 3);
    #pragma unroll
    for (int j = 0; j < 8; ++j) {
      int ci, ky;
      bool ok = (ch < 30) && (j < 5);
      if (s < 6)       { ci = s;        ky = quad; }
      else if (s == 6) { ci = quad;     ky = 4;    }
      else             { ci = 4 + quad; ky = 4; ok = ok && (quad < 2); }
      float v = 0.0f;
      if (ok) v = w1[ch * 150 + ci * 25 + ky * 5 + j];
      dst[j] = f2h(v);
    }
  }
}

// ---------------------------------------------------------------------------
// conv1 + fire + maxpool2x2. Pool-interleaved M (4 C/D rows = one 2x2 pool
// window). Per step: 2 dwordx4 A loads + 4 cvt_pkrtz + 2 B b128 + 2 MFMA.
// grid 11760 x 256 (4 waves x 16 rows). No LDS, no barrier.
// ---------------------------------------------------------------------------
__global__ __launch_bounds__(256) void conv1_mfma(
    const float* __restrict__ in32,
    const unsigned short* __restrict__ bp1,
    unsigned short* __restrict__ spk16)
{
  const int tid = threadIdx.x;
  const int wave = tid >> 6, lane = tid & 63;
  const int quad = lane >> 4, nl = lane & 15;
  const int m0 = blockIdx.x * 64 + wave * 16;

  const int m = m0 + nl;
  const int sub = m & 3, g = m >> 2;
  const int gx = g % 112, t = g / 112;
  const int gy = t % 112, n = t / 112;
  const int y0 = gy * 2 + (sub >> 1);          // padded coords
  const int x0 = gx * 2 + (sub & 1);

  const float* nbase = in32 + (size_t)n * (6 * 51984);
  const float* rq  = nbase + (y0 + quad) * 228 + x0;
  const float* r4a = nbase + (size_t)quad * 51984 + (y0 + 4) * 228 + x0;
  const float* r4b = nbase + (size_t)(4 + (quad & 1)) * 51984 + (y0 + 4) * 228 + x0;

  f32x4 acc0 = {0.f,0.f,0.f,0.f}, acc1 = {0.f,0.f,0.f,0.f};
  const half8* bptr = (const half8*)bp1;

  #pragma unroll
  for (int s = 0; s < 8; ++s) {
    const float* p = (s < 6) ? (rq + s * 51984) : (s == 6 ? r4a : r4b);
    const f32x4u v0 = *(const f32x4u*)p;
    const f32x4u v1 = *(const f32x4u*)(p + 4);
    union { half8 h; fp16x2 h2[4]; } A;
    A.h2[0] = __builtin_amdgcn_cvt_pkrtz(v0.x, v0.y);
    A.h2[1] = __builtin_amdgcn_cvt_pkrtz(v0.z, v0.w);
    A.h2[2] = __builtin_amdgcn_cvt_pkrtz(v1.x, v1.y);
    A.h2[3] = __builtin_amdgcn_cvt_pkrtz(v1.z, v1.w);
    const half8 b0 = bptr[(s * 2 + 0) * 64 + lane];
    const half8 b1 = bptr[(s * 2 + 1) * 64 + lane];
    acc0 = __builtin_amdgcn_mfma_f32_16x16x32_f16(A.h, b0, acc0, 0, 0, 0);
    acc1 = __builtin_amdgcn_mfma_f32_16x16x32_f16(A.h, b1, acc1, 0, 0, 0);
  }

  const int gq = (m0 >> 2) + quad;
  const int pgx = gq % 112, tq = gq / 112;
  const int pgy = tq % 112, nq = tq / 112;
  const bool f0 = (acc0[0] > POT1_T) | (acc0[1] > POT1_T) |
                  (acc0[2] > POT1_T) | (acc0[3] > POT1_T);
  const bool f1 = (acc1[0] > POT1_T) | (acc1[1] > POT1_T) |
                  (acc1[2] > POT1_T) | (acc1[3] > POT1_T);
  const size_t o = ((size_t)(nq * 114 + pgy + 1) * 114 + (pgx + 1)) * 32 + nl;
  spk16[o] = f0 ? (unsigned short)0x3C00 : (unsigned short)0;
  if (nl < 14)                                  // ch nl+16 < 30
    spk16[o + 16] = f1 ? (unsigned short)0x3C00 : (unsigned short)0;
}

// ---------------------------------------------------------------------------
// conv2 + fire: M=32/wave (2 chunks of 16 rows sharing B-frags), N=240
// (15 subtiles). Per step: 2 A b128 loads + 15 B b128 loads + 30 MFMAs.
// B L2 traffic halved vs M=16/wave. Nontemporal output stores.
// grid 1470 x 256.
// ---------------------------------------------------------------------------
__global__ __launch_bounds__(256, 2) void conv2_mfma(
    const unsigned short* __restrict__ spk16,
    const unsigned short* __restrict__ bp2,
    float* __restrict__ out_spk, float* __restrict__ out_pot)
{
  const int tid = threadIdx.x;
  const int wave = tid >> 6, lane = tid & 63;
  const int quad = lane >> 4, nl = lane & 15;
  const int m0 = blockIdx.x * 128 + wave * 32;

  // two M chunks: rows m0+nl and m0+16+nl
  const unsigned short* abase[2];
  #pragma unroll
  for (int c = 0; c < 2; ++c) {
    const int m = m0 + c * 16 + nl;
    const int x = m % 112, t = m / 112;
    const int y = t % 112, n = t / 112;
    abase[c] = spk16 + ((size_t)(n * 114 + y) * 114 + x) * 32 + quad * 8;
  }

  f32x4 acc[2][15];
  #pragma unroll
  for (int c = 0; c < 2; ++c)
    #pragma unroll
    for (int u = 0; u < 15; ++u) acc[c][u] = (f32x4){0.f, 0.f, 0.f, 0.f};

  const half8* bptr = (const half8*)bp2;
  #pragma unroll
  for (int s = 0; s < 9; ++s) {                // s = ky*3+kx
    const int ky = s / 3, kx = s - ky * 3;     // compile-time under unroll
    const half8 a0 = *(const half8*)(abase[0] + (ky * 114 + kx) * 32);
    const half8 a1 = *(const half8*)(abase[1] + (ky * 114 + kx) * 32);
    #pragma unroll
    for (int u = 0; u < 15; ++u) {
      const half8 b = bptr[(s * 15 + u) * 64 + lane];
      acc[0][u] = __builtin_amdgcn_mfma_f32_16x16x32_f16(a0, b, acc[0][u], 0, 0, 0);
      acc[1][u] = __builtin_amdgcn_mfma_f32_16x16x32_f16(a1, b, acc[1][u], 0, 0, 0);
    }
  }

  // epilogue: chunk c rows mrow..mrow+3 contiguous in x (m0%4==0, 112%4==0)
  #pragma unroll
  for (int c = 0; c < 2; ++c) {
    const int mrow = m0 + c * 16 + quad * 4;
    const int xr = mrow % 112, tr = mrow / 112;
    const int yr = tr % 112, nr = tr / 112;
    #pragma unroll
    for (int u = 0; u < 15; ++u) {
      const int ch = u * 16 + nl;
      const size_t o = ((size_t)(nr * 240 + ch) * 112 + yr) * 112 + xr;
      f32x4 sp, pt;
      #pragma unroll
      for (int rr = 0; rr < 4; ++rr) {
        const float p = acc[c][u][rr];
        const bool f = p > POT2_T;
        sp[rr] = f ? 1.0f : 0.0f;
        pt[rr] = f ? p : 0.0f;
      }
      __builtin_nontemporal_store(sp, (f32x4*)(out_spk + o));
      __builtin_nontemporal_store(pt, (f32x4*)(out_pot + o));
    }
  }
}

// ---------------------------------------------------------------------------
extern "C" void kernel_launch(void* const* d_in, const int* in_sizes, int n_in,
                              void* d_out, int out_size, void* d_ws, size_t ws_size,
                              hipStream_t stream)
{
  const float* in = (const float*)d_in[0];
  const float* w1 = (const float*)d_in[1];
  const float* w2 = (const float*)d_in[2];
  float* out = (float*)d_out;

  unsigned short* spk16 = (unsigned short*)d_ws;
  unsigned short* bp2   = (unsigned short*)((char*)d_ws + BP2_OFF);
  unsigned short* bp1   = (unsigned short*)((char*)d_ws + BP1_OFF);
  float*          in32  = (float*)((char*)d_ws + IN32_OFF);

  (void)hipMemsetAsync(d_ws, 0, SPK_BYTES, stream);  // spike pad ring + ch 30/31
  prep<<<PAD_BLOCKS + 151, 256, 0, stream>>>(in, w1, w2, in32, bp2, bp1);
  conv1_mfma<<<11760, 256, 0, stream>>>(in32, bp1, spk16);
  conv2_mfma<<<1470, 256, 0, stream>>>(
      spk16, bp2, out, out + (size_t)15 * 240 * 112 * 112);
}

// Round 7
// 482.328 us; speedup vs baseline: 1.8367x; 1.0691x over previous
//
#include <hip/hip_runtime.h>
#include <stdint.h>

// SNN forward (Mozafari 2018), max_layer==2:
//   pad(2) -> conv1(30,6,5,5) -> fire(>15) -> maxpool2x2 -> pad(1)
//   -> conv2(240,30,3,3) -> fire(>10) -> out = spk ++ pot (f32)
//
// f16 MFMA implicit GEMM. K-mappings make every A-fragment a contiguous
// vector load:
//  conv1: step s -> (ci,ky), quad -> row, j -> kx (kx>=5: B=0).
//         A-frag = 8 consecutive f32 -> 2x dwordx4 + 4x v_cvt_pkrtz. K=256.
//         M=32/wave: 2 chunks share each B-frag.
//  conv2: step s = ky*3+kx, lane k-index = ci (ch-interleaved spike map
//         (n,y,x,32)) -> A-frag = one aligned b128 load. K=288.
//         Block = 8 waves x M=32; B-frags staged in LDS (46 KB, 5 of 15
//         N-subtiles per block, gridDim.y=3) -> B L2 traffic 811->100 MB.
// Nontemporal stores for the 361 MB output (don't thrash L2).

typedef _Float16 half8  __attribute__((ext_vector_type(8)));
typedef __fp16   fp16x2 __attribute__((ext_vector_type(2)));
typedef float f32x4  __attribute__((ext_vector_type(4)));
typedef float f32x4u __attribute__((ext_vector_type(4), aligned(4)));

#define POT1_T 15.0f
#define POT2_T 10.0f

// ---- ws layout (all 16B aligned) ----
#define SPK_ELEMS  (15*114*114*32)            // 6,238,080 f16 (ch-interleaved, padded)
#define SPK_BYTES  (SPK_ELEMS*2)              // 12,476,160
#define BP2_OFF    SPK_BYTES
#define BP2_BYTES  (9*15*64*8*2)              // 138,240
#define BP1_OFF    (BP2_OFF + BP2_BYTES)
#define BP1_BYTES  (8*2*64*8*2)               // 16,384
#define IN32_OFF   (BP1_OFF + BP1_BYTES)
#define IN32_ELEMS (90*228*228)               // 4,678,560 f32 (padded input)

#define PAD_BLOCKS ((IN32_ELEMS + 255) / 256) // 18276

__device__ __forceinline__ unsigned short f2h(float v) {
  union { _Float16 h; unsigned short u; } c;
  c.h = (_Float16)v;                          // RNE
  return c.u;
}

// ---------------------------------------------------------------------------
// prep: pad input to f32 (n*6,228,228)  +  pack weights to MFMA B-frag layout
// [step][nsub][lane][8].
// ---------------------------------------------------------------------------
__global__ __launch_bounds__(256) void prep(
    const float* __restrict__ in, const float* __restrict__ w1,
    const float* __restrict__ w2, float* __restrict__ in32,
    unsigned short* __restrict__ bp2, unsigned short* __restrict__ bp1)
{
  const int blk = blockIdx.x;
  if (blk < PAD_BLOCKS) {
    const int i = blk * 256 + threadIdx.x;
    if (i >= IN32_ELEMS) return;
    const int xx = i % 228, t = i / 228;
    const int yy = t % 228, c = t / 228;
    const int xi = xx - 2, yi = yy - 2;
    float v = 0.0f;
    if ((unsigned)xi < 224u && (unsigned)yi < 224u)
      v = in[(c * 224 + yi) * 224 + xi];
    in32[i] = v;
    return;
  }
  if (threadIdx.x >= 64) return;
  const int b = blk - PAD_BLOCKS;              // 0..150
  const int lane = threadIdx.x;
  const int quad = lane >> 4, nl = lane & 15;
  if (b < 135) {                               // conv2: 9 steps x 15 nsub
    const int s = b / 15, nsub = b - s * 15;   // s = ky*3+kx
    const int ch = nsub * 16 + nl;
    unsigned short* dst = bp2 + (((s * 15 + nsub) * 64 + lane) << 3);
    #pragma unroll
    for (int j = 0; j < 8; ++j) {
      const int ci = quad * 8 + j;
      dst[j] = f2h((ci < 30) ? w2[ch * 270 + ci * 9 + s] : 0.0f);
    }
  } else {                                     // conv1: 8 steps x 2 nsub
    const int bb = b - 135;
    const int s = bb >> 1, nsub = bb & 1;
    const int ch = nsub * 16 + nl;
    unsigned short* dst = bp1 + (((s * 2 + nsub) * 64 + lane) << 3);
    #pragma unroll
    for (int j = 0; j < 8; ++j) {
      int ci, ky;
      bool ok = (ch < 30) && (j < 5);
      if (s < 6)       { ci = s;        ky = quad; }
      else if (s == 6) { ci = quad;     ky = 4;    }
      else             { ci = 4 + quad; ky = 4; ok = ok && (quad < 2); }
      float v = 0.0f;
      if (ok) v = w1[ch * 150 + ci * 25 + ky * 5 + j];
      dst[j] = f2h(v);
    }
  }
}

// ---------------------------------------------------------------------------
// conv1 + fire + maxpool2x2. Pool-interleaved M (4 C/D rows = one 2x2 pool
// window). M=32/wave: 2 chunks of 16 rows share each B-frag.
// grid 5880 x 256 (4 waves x 32 rows). No LDS, no barrier.
// ---------------------------------------------------------------------------
__global__ __launch_bounds__(256) void conv1_mfma(
    const float* __restrict__ in32,
    const unsigned short* __restrict__ bp1,
    unsigned short* __restrict__ spk16)
{
  const int tid = threadIdx.x;
  const int wave = tid >> 6, lane = tid & 63;
  const int quad = lane >> 4, nl = lane & 15;
  const int m0 = blockIdx.x * 128 + wave * 32;

  const float* rq[2];
  const float* r4a[2];
  const float* r4b[2];
  #pragma unroll
  for (int c = 0; c < 2; ++c) {
    const int m = m0 + c * 16 + nl;
    const int sub = m & 3, g = m >> 2;
    const int gx = g % 112, t = g / 112;
    const int gy = t % 112, n = t / 112;
    const int y0 = gy * 2 + (sub >> 1);        // padded coords
    const int x0 = gx * 2 + (sub & 1);
    const float* nbase = in32 + (size_t)n * (6 * 51984);
    rq[c]  = nbase + (y0 + quad) * 228 + x0;
    r4a[c] = nbase + (size_t)quad * 51984 + (y0 + 4) * 228 + x0;
    r4b[c] = nbase + (size_t)(4 + (quad & 1)) * 51984 + (y0 + 4) * 228 + x0;
  }

  f32x4 acc[2][2];
  #pragma unroll
  for (int c = 0; c < 2; ++c)
    #pragma unroll
    for (int u = 0; u < 2; ++u) acc[c][u] = (f32x4){0.f, 0.f, 0.f, 0.f};

  const half8* bptr = (const half8*)bp1;
  #pragma unroll
  for (int s = 0; s < 8; ++s) {
    const half8 b0 = bptr[(s * 2 + 0) * 64 + lane];
    const half8 b1 = bptr[(s * 2 + 1) * 64 + lane];
    #pragma unroll
    for (int c = 0; c < 2; ++c) {
      const float* p = (s < 6) ? (rq[c] + s * 51984) : (s == 6 ? r4a[c] : r4b[c]);
      const f32x4u v0 = *(const f32x4u*)p;
      const f32x4u v1 = *(const f32x4u*)(p + 4);
      union { half8 h; fp16x2 h2[4]; } A;
      A.h2[0] = __builtin_amdgcn_cvt_pkrtz(v0.x, v0.y);
      A.h2[1] = __builtin_amdgcn_cvt_pkrtz(v0.z, v0.w);
      A.h2[2] = __builtin_amdgcn_cvt_pkrtz(v1.x, v1.y);
      A.h2[3] = __builtin_amdgcn_cvt_pkrtz(v1.z, v1.w);
      acc[c][0] = __builtin_amdgcn_mfma_f32_16x16x32_f16(A.h, b0, acc[c][0], 0, 0, 0);
      acc[c][1] = __builtin_amdgcn_mfma_f32_16x16x32_f16(A.h, b1, acc[c][1], 0, 0, 0);
    }
  }

  #pragma unroll
  for (int c = 0; c < 2; ++c) {
    const int gq = ((m0 + c * 16) >> 2) + quad;
    const int pgx = gq % 112, tq = gq / 112;
    const int pgy = tq % 112, nq = tq / 112;
    const bool f0 = (acc[c][0][0] > POT1_T) | (acc[c][0][1] > POT1_T) |
                    (acc[c][0][2] > POT1_T) | (acc[c][0][3] > POT1_T);
    const bool f1 = (acc[c][1][0] > POT1_T) | (acc[c][1][1] > POT1_T) |
                    (acc[c][1][2] > POT1_T) | (acc[c][1][3] > POT1_T);
    const size_t o = ((size_t)(nq * 114 + pgy + 1) * 114 + (pgx + 1)) * 32 + nl;
    spk16[o] = f0 ? (unsigned short)0x3C00 : (unsigned short)0;
    if (nl < 14)                                // ch nl+16 < 30
      spk16[o + 16] = f1 ? (unsigned short)0x3C00 : (unsigned short)0;
  }
}

// ---------------------------------------------------------------------------
// conv2 + fire: block = 8 waves x M=32 = 256 rows; N = 5 subtiles (80 ch),
// gridDim.y = 3 covers 240. B-frags staged once per block into LDS (46 KB):
// B L2 traffic per block 46 KB instead of 46 KB/wave. Per step per wave:
// 2 A b128 + 5 ds_read_b128 + 10 MFMA. Nontemporal output stores.
// grid (735, 3) x 512.
// ---------------------------------------------------------------------------
#define C2_NSUB 5
__global__ __launch_bounds__(512) void conv2_mfma(
    const unsigned short* __restrict__ spk16,
    const unsigned short* __restrict__ bp2,
    float* __restrict__ out_spk, float* __restrict__ out_pot)
{
  __shared__ __attribute__((aligned(16))) unsigned short Blds[C2_NSUB * 9 * 64 * 8];

  const int tid = threadIdx.x;
  const int ntile = blockIdx.y;                // 0..2, subtiles ntile*5..+4
  // stage 5 subtiles x 9 steps x 64 lanes x 16B = 2880 uint4
  for (int i = tid; i < 2880; i += 512) {
    const int su = i / 576, rem = i - su * 576;    // rem = s*64+lane
    ((uint4*)Blds)[su * 576 + rem] =
        ((const uint4*)bp2)[((rem >> 6) * 15 + ntile * C2_NSUB + su) * 64 + (rem & 63)];
  }
  __syncthreads();

  const int wave = tid >> 6, lane = tid & 63;
  const int quad = lane >> 4, nl = lane & 15;
  const int m0 = blockIdx.x * 256 + wave * 32;

  const unsigned short* abase[2];
  #pragma unroll
  for (int c = 0; c < 2; ++c) {
    const int m = m0 + c * 16 + nl;
    const int x = m % 112, t = m / 112;
    const int y = t % 112, n = t / 112;
    abase[c] = spk16 + ((size_t)(n * 114 + y) * 114 + x) * 32 + quad * 8;
  }

  f32x4 acc[2][C2_NSUB];
  #pragma unroll
  for (int c = 0; c < 2; ++c)
    #pragma unroll
    for (int u = 0; u < C2_NSUB; ++u) acc[c][u] = (f32x4){0.f, 0.f, 0.f, 0.f};

  const half8* blds = (const half8*)Blds;
  #pragma unroll
  for (int s = 0; s < 9; ++s) {                // s = ky*3+kx
    const int ky = s / 3, kx = s - ky * 3;     // compile-time under unroll
    const half8 a0 = *(const half8*)(abase[0] + (ky * 114 + kx) * 32);
    const half8 a1 = *(const half8*)(abase[1] + (ky * 114 + kx) * 32);
    #pragma unroll
    for (int u = 0; u < C2_NSUB; ++u) {
      const half8 b = blds[(u * 9 + s) * 64 + lane];
      acc[0][u] = __builtin_amdgcn_mfma_f32_16x16x32_f16(a0, b, acc[0][u], 0, 0, 0);
      acc[1][u] = __builtin_amdgcn_mfma_f32_16x16x32_f16(a1, b, acc[1][u], 0, 0, 0);
    }
  }

  // epilogue: chunk c rows mrow..mrow+3 contiguous in x (m0%4==0, 112%4==0)
  #pragma unroll
  for (int c = 0; c < 2; ++c) {
    const int mrow = m0 + c * 16 + quad * 4;
    const int xr = mrow % 112, tr = mrow / 112;
    const int yr = tr % 112, nr = tr / 112;
    #pragma unroll
    for (int u = 0; u < C2_NSUB; ++u) {
      const int ch = (ntile * C2_NSUB + u) * 16 + nl;
      const size_t o = ((size_t)(nr * 240 + ch) * 112 + yr) * 112 + xr;
      f32x4 sp, pt;
      #pragma unroll
      for (int rr = 0; rr < 4; ++rr) {
        const float p = acc[c][u][rr];
        const bool f = p > POT2_T;
        sp[rr] = f ? 1.0f : 0.0f;
        pt[rr] = f ? p : 0.0f;
      }
      __builtin_nontemporal_store(sp, (f32x4*)(out_spk + o));
      __builtin_nontemporal_store(pt, (f32x4*)(out_pot + o));
    }
  }
}

// ---------------------------------------------------------------------------
extern "C" void kernel_launch(void* const* d_in, const int* in_sizes, int n_in,
                              void* d_out, int out_size, void* d_ws, size_t ws_size,
                              hipStream_t stream)
{
  const float* in = (const float*)d_in[0];
  const float* w1 = (const float*)d_in[1];
  const float* w2 = (const float*)d_in[2];
  float* out = (float*)d_out;

  unsigned short* spk16 = (unsigned short*)d_ws;
  unsigned short* bp2   = (unsigned short*)((char*)d_ws + BP2_OFF);
  unsigned short* bp1   = (unsigned short*)((char*)d_ws + BP1_OFF);
  float*          in32  = (float*)((char*)d_ws + IN32_OFF);

  (void)hipMemsetAsync(d_ws, 0, SPK_BYTES, stream);  // spike pad ring + ch 30/31
  prep<<<PAD_BLOCKS + 151, 256, 0, stream>>>(in, w1, w2, in32, bp2, bp1);
  conv1_mfma<<<5880, 256, 0, stream>>>(in32, bp1, spk16);
  conv2_mfma<<<dim3(735, 3), 512, 0, stream>>>(
      spk16, bp2, out, out + (size_t)15 * 240 * 112 * 112);
}

// Round 8
// 465.043 us; speedup vs baseline: 1.9050x; 1.0372x over previous
//
#include <hip/hip_runtime.h>
#include <stdint.h>

// SNN forward (Mozafari 2018), max_layer==2:
//   pad(2) -> conv1(30,6,5,5) -> fire(>15) -> maxpool2x2 -> pad(1)
//   -> conv2(240,30,3,3) -> fire(>10) -> out = spk ++ pot (f32)
//
// f16 MFMA implicit GEMM. Every A-fragment is ONE b128 load:
//  conv1: step s -> (ci,ky), quad -> row, j -> kx (kx>=5: B=0). K=256.
//         Padded input stored as f16 TWICE (ina, inb = ina shifted by one
//         element) so odd-x0 lanes load 4B-aligned b128 too. M=64/wave.
//  conv2: step s = ky*3+kx, lane k-index = ci (ch-interleaved spike map
//         (n,y,x,32)). K=288. M=64/wave (4 chunks share each LDS B ds_read),
//         B staged in LDS (46 KB, 5 of 15 N-subtiles, gridDim.y=3).
// Nontemporal stores for the 361 MB output (don't thrash L2).

typedef _Float16 half8  __attribute__((ext_vector_type(8)));
typedef _Float16 half8u __attribute__((ext_vector_type(8), aligned(4)));
typedef float f32x4  __attribute__((ext_vector_type(4)));

#define POT1_T 15.0f
#define POT2_T 10.0f

// ---- ws layout (all 16B aligned) ----
#define SPK_ELEMS  (15*114*114*32)            // 6,238,080 f16 (ch-interleaved, padded)
#define SPK_BYTES  (SPK_ELEMS*2)              // 12,476,160
#define BP2_OFF    SPK_BYTES
#define BP2_BYTES  (9*15*64*8*2)              // 138,240
#define BP1_OFF    (BP2_OFF + BP2_BYTES)
#define BP1_BYTES  (8*2*64*8*2)               // 16,384
#define IN16_OFF   (BP1_OFF + BP1_BYTES)      // 12,630,784 (16B aligned)
#define IN16_ELEMS (90*228*228)               // 4,678,560 f16 per copy
// ina at IN16_OFF; inb (shifted copy) right after; +16B guard. ~31.3 MB total.

#define PAD_BLOCKS ((IN16_ELEMS + 255) / 256) // 18276

__device__ __forceinline__ unsigned short f2h(float v) {
  union { _Float16 h; unsigned short u; } c;
  c.h = (_Float16)v;                          // RNE
  return c.u;
}

// ---------------------------------------------------------------------------
// prep: pad input -> f16, dual copies (ina[i]=v(i), inb[i-1]=v(i)), plus
// weight packing to MFMA B-frag layout [step][nsub][lane][8].
// ---------------------------------------------------------------------------
__global__ __launch_bounds__(256) void prep(
    const float* __restrict__ in, const float* __restrict__ w1,
    const float* __restrict__ w2, unsigned short* __restrict__ ina,
    unsigned short* __restrict__ bp2, unsigned short* __restrict__ bp1)
{
  const int blk = blockIdx.x;
  if (blk < PAD_BLOCKS) {
    const int i = blk * 256 + threadIdx.x;
    if (i >= IN16_ELEMS) return;
    const int xx = i % 228, t = i / 228;
    const int yy = t % 228, c = t / 228;
    const int xi = xx - 2, yi = yy - 2;
    float v = 0.0f;
    if ((unsigned)xi < 224u && (unsigned)yi < 224u)
      v = in[(c * 224 + yi) * 224 + xi];
    const unsigned short h = f2h(v);
    unsigned short* inb = ina + IN16_ELEMS;
    ina[i] = h;
    if (i > 0) inb[i - 1] = h;
    if (i == IN16_ELEMS - 1) inb[i] = 0;
    return;
  }
  if (threadIdx.x >= 64) return;
  const int b = blk - PAD_BLOCKS;              // 0..150
  const int lane = threadIdx.x;
  const int quad = lane >> 4, nl = lane & 15;
  if (b < 135) {                               // conv2: 9 steps x 15 nsub
    const int s = b / 15, nsub = b - s * 15;   // s = ky*3+kx
    const int ch = nsub * 16 + nl;
    unsigned short* dst = bp2 + (((s * 15 + nsub) * 64 + lane) << 3);
    #pragma unroll
    for (int j = 0; j < 8; ++j) {
      const int ci = quad * 8 + j;
      dst[j] = f2h((ci < 30) ? w2[ch * 270 + ci * 9 + s] : 0.0f);
    }
  } else {                                     // conv1: 8 steps x 2 nsub
    const int bb = b - 135;
    const int s = bb >> 1, nsub = bb & 1;
    const int ch = nsub * 16 + nl;
    unsigned short* dst = bp1 + (((s * 2 + nsub) * 64 + lane) << 3);
    #pragma unroll
    for (int j = 0; j < 8; ++j) {
      int ci, ky;
      bool ok = (ch < 30) && (j < 5);
      if (s < 6)       { ci = s;        ky = quad; }
      else if (s == 6) { ci = quad;     ky = 4;    }
      else             { ci = 4 + quad; ky = 4; ok = ok && (quad < 2); }
      float v = 0.0f;
      if (ok) v = w1[ch * 150 + ci * 25 + ky * 5 + j];
      dst[j] = f2h(v);
    }
  }
}

// ---------------------------------------------------------------------------
// conv1 + fire + maxpool2x2. Pool-interleaved M (4 C/D rows = one 2x2 pool
// window). M=64/wave: 4 chunks of 16 rows share each B-frag. A-frag = one
// 4B-aligned b128 from the parity-matched input copy (parity = nl&1, since
// m0 is always even). grid 2940 x 256 (4 waves x 64 rows). No LDS.
// ---------------------------------------------------------------------------
__global__ __launch_bounds__(256) void conv1_mfma(
    const unsigned short* __restrict__ in16,   // ina; inb = ina + IN16_ELEMS
    const unsigned short* __restrict__ bp1,
    unsigned short* __restrict__ spk16)
{
  const int tid = threadIdx.x;
  const int wave = tid >> 6, lane = tid & 63;
  const int quad = lane >> 4, nl = lane & 15;
  const int m0 = blockIdx.x * 256 + wave * 64;

  // parity of x0 is lane-constant: p = nl & 1 (m0, c*16 even)
  const unsigned short* base = in16 + ((nl & 1) ? (IN16_ELEMS - 1) : 0);

  unsigned o_q[4], o_a[4], o_b[4];
  #pragma unroll
  for (int c = 0; c < 4; ++c) {
    const int m = m0 + c * 16 + nl;
    const int sub = m & 3, g = m >> 2;
    const int gx = g % 112, t = g / 112;
    const int gy = t % 112, n = t / 112;
    const int y0 = gy * 2 + (sub >> 1);        // padded coords
    const int x0 = gx * 2 + (sub & 1);
    const unsigned nb = (unsigned)n * 311904u; // 6*51984
    o_q[c] = nb + (unsigned)((y0 + quad) * 228 + x0);
    o_a[c] = nb + (unsigned)quad * 51984u + (unsigned)((y0 + 4) * 228 + x0);
    o_b[c] = nb + (unsigned)(4 + (quad & 1)) * 51984u + (unsigned)((y0 + 4) * 228 + x0);
  }

  f32x4 acc[4][2];
  #pragma unroll
  for (int c = 0; c < 4; ++c) {
    acc[c][0] = (f32x4){0.f, 0.f, 0.f, 0.f};
    acc[c][1] = (f32x4){0.f, 0.f, 0.f, 0.f};
  }

  const half8* bptr = (const half8*)bp1;
  #pragma unroll
  for (int s = 0; s < 8; ++s) {
    const half8 b0 = bptr[(s * 2 + 0) * 64 + lane];
    const half8 b1 = bptr[(s * 2 + 1) * 64 + lane];
    #pragma unroll
    for (int c = 0; c < 4; ++c) {
      const unsigned off = (s < 6) ? (o_q[c] + (unsigned)s * 51984u)
                                   : (s == 6 ? o_a[c] : o_b[c]);
      const half8 A = *(const half8u*)(base + off);
      acc[c][0] = __builtin_amdgcn_mfma_f32_16x16x32_f16(A, b0, acc[c][0], 0, 0, 0);
      acc[c][1] = __builtin_amdgcn_mfma_f32_16x16x32_f16(A, b1, acc[c][1], 0, 0, 0);
    }
  }

  #pragma unroll
  for (int c = 0; c < 4; ++c) {
    const int gq = ((m0 + c * 16) >> 2) + quad;
    const int pgx = gq % 112, tq = gq / 112;
    const int pgy = tq % 112, nq = tq / 112;
    const bool f0 = (acc[c][0][0] > POT1_T) | (acc[c][0][1] > POT1_T) |
                    (acc[c][0][2] > POT1_T) | (acc[c][0][3] > POT1_T);
    const bool f1 = (acc[c][1][0] > POT1_T) | (acc[c][1][1] > POT1_T) |
                    (acc[c][1][2] > POT1_T) | (acc[c][1][3] > POT1_T);
    const size_t o = ((size_t)(nq * 114 + pgy + 1) * 114 + (pgx + 1)) * 32 + nl;
    spk16[o] = f0 ? (unsigned short)0x3C00 : (unsigned short)0;
    if (nl < 14)                                // ch nl+16 < 30
      spk16[o + 16] = f1 ? (unsigned short)0x3C00 : (unsigned short)0;
  }
}

// ---------------------------------------------------------------------------
// conv2 + fire: block = 4 waves x M=64 = 256 rows; N = 5 subtiles (80 ch),
// gridDim.y = 3 covers 240. B staged in LDS (46 KB); each ds_read_b128 of B
// feeds 4 MFMAs (4 M-chunks). Per wave-step: 4 A b128 + 5 ds_read_b128 +
// 20 MFMA -> MFMA/write-bound, not LDS-bound. Nontemporal output stores.
// grid (735, 3) x 256.
// ---------------------------------------------------------------------------
#define C2_NSUB 5
__global__ __launch_bounds__(256, 3) void conv2_mfma(
    const unsigned short* __restrict__ spk16,
    const unsigned short* __restrict__ bp2,
    float* __restrict__ out_spk, float* __restrict__ out_pot)
{
  __shared__ __attribute__((aligned(16))) unsigned short Blds[C2_NSUB * 9 * 64 * 8];

  const int tid = threadIdx.x;
  const int ntile = blockIdx.y;                // 0..2, subtiles ntile*5..+4
  // stage 5 subtiles x 9 steps x 64 lanes x 16B = 2880 uint4
  for (int i = tid; i < 2880; i += 256) {
    const int su = i / 576, rem = i - su * 576;    // rem = s*64+lane
    ((uint4*)Blds)[su * 576 + rem] =
        ((const uint4*)bp2)[((rem >> 6) * 15 + ntile * C2_NSUB + su) * 64 + (rem & 63)];
  }
  __syncthreads();

  const int wave = tid >> 6, lane = tid & 63;
  const int quad = lane >> 4, nl = lane & 15;
  const int m0 = blockIdx.x * 256 + wave * 64;

  const unsigned short* abase[4];
  #pragma unroll
  for (int c = 0; c < 4; ++c) {
    const int m = m0 + c * 16 + nl;
    const int x = m % 112, t = m / 112;
    const int y = t % 112, n = t / 112;
    abase[c] = spk16 + ((size_t)(n * 114 + y) * 114 + x) * 32 + quad * 8;
  }

  f32x4 acc[4][C2_NSUB];
  #pragma unroll
  for (int c = 0; c < 4; ++c)
    #pragma unroll
    for (int u = 0; u < C2_NSUB; ++u) acc[c][u] = (f32x4){0.f, 0.f, 0.f, 0.f};

  const half8* blds = (const half8*)Blds;
  #pragma unroll
  for (int s = 0; s < 9; ++s) {                // s = ky*3+kx
    const int ky = s / 3, kx = s - ky * 3;     // compile-time under unroll
    half8 a[4];
    #pragma unroll
    for (int c = 0; c < 4; ++c)
      a[c] = *(const half8*)(abase[c] + (ky * 114 + kx) * 32);
    #pragma unroll
    for (int u = 0; u < C2_NSUB; ++u) {
      const half8 b = blds[(u * 9 + s) * 64 + lane];
      #pragma unroll
      for (int c = 0; c < 4; ++c)
        acc[c][u] = __builtin_amdgcn_mfma_f32_16x16x32_f16(a[c], b, acc[c][u], 0, 0, 0);
    }
  }

  // epilogue: chunk c rows mrow..mrow+3 contiguous in x (m0%4==0, 112%4==0)
  #pragma unroll
  for (int c = 0; c < 4; ++c) {
    const int mrow = m0 + c * 16 + quad * 4;
    const int xr = mrow % 112, tr = mrow / 112;
    const int yr = tr % 112, nr = tr / 112;
    #pragma unroll
    for (int u = 0; u < C2_NSUB; ++u) {
      const int ch = (ntile * C2_NSUB + u) * 16 + nl;
      const size_t o = ((size_t)(nr * 240 + ch) * 112 + yr) * 112 + xr;
      f32x4 sp, pt;
      #pragma unroll
      for (int rr = 0; rr < 4; ++rr) {
        const float p = acc[c][u][rr];
        const bool f = p > POT2_T;
        sp[rr] = f ? 1.0f : 0.0f;
        pt[rr] = f ? p : 0.0f;
      }
      __builtin_nontemporal_store(sp, (f32x4*)(out_spk + o));
      __builtin_nontemporal_store(pt, (f32x4*)(out_pot + o));
    }
  }
}

// ---------------------------------------------------------------------------
extern "C" void kernel_launch(void* const* d_in, const int* in_sizes, int n_in,
                              void* d_out, int out_size, void* d_ws, size_t ws_size,
                              hipStream_t stream)
{
  const float* in = (const float*)d_in[0];
  const float* w1 = (const float*)d_in[1];
  const float* w2 = (const float*)d_in[2];
  float* out = (float*)d_out;

  unsigned short* spk16 = (unsigned short*)d_ws;
  unsigned short* bp2   = (unsigned short*)((char*)d_ws + BP2_OFF);
  unsigned short* bp1   = (unsigned short*)((char*)d_ws + BP1_OFF);
  unsigned short* ina   = (unsigned short*)((char*)d_ws + IN16_OFF);

  (void)hipMemsetAsync(d_ws, 0, SPK_BYTES, stream);  // spike pad ring + ch 30/31
  prep<<<PAD_BLOCKS + 151, 256, 0, stream>>>(in, w1, w2, ina, bp2, bp1);
  conv1_mfma<<<2940, 256, 0, stream>>>(ina, bp1, spk16);
  conv2_mfma<<<dim3(735, 3), 256, 0, stream>>>(
      spk16, bp2, out, out + (size_t)15 * 240 * 112 * 112);
}